// Round 9
// baseline (704.230 us; speedup 1.0000x reference)
//
#include <hip/hip_runtime.h>
#include <stdint.h>

#define NN 100000
#define NE 400000
#define FIN 602
#define HID 256
#define NC 42
#define NB_SCAN 98   // ceil(NN/1024)

typedef __attribute__((ext_vector_type(8))) short bf16x8;
typedef __attribute__((ext_vector_type(4))) float f32x4;
typedef __attribute__((ext_vector_type(2))) float f32x2;
typedef __attribute__((ext_vector_type(4))) short s16x4;

static __device__ __forceinline__ short f2bf(float f) {
  union { float f; uint32_t u; } v; v.f = f;
  uint32_t r = (v.u + 0x7fffu + ((v.u >> 16) & 1u)) >> 16;
  return (short)(uint16_t)r;
}
static __device__ __forceinline__ float bf2f(short s) {
  union { uint32_t u; float f; } v; v.u = ((uint32_t)(uint16_t)s) << 16;
  return v.f;
}
// HW packed f32->bf16 (RNE)
static __device__ __forceinline__ uint32_t cvtpk(float a, float b) {
  uint32_t r;
  asm("v_cvt_pk_bf16_f32 %0, %1, %2" : "=v"(r) : "v"(a), "v"(b));
  return r;
}
static __device__ __forceinline__ bf16x8 pack8q(f32x4 a, f32x4 b) {
  union { bf16x8 v; uint32_t u[4]; } r;
  r.u[0] = cvtpk(a[0], a[1]);
  r.u[1] = cvtpk(a[2], a[3]);
  r.u[2] = cvtpk(b[0], b[1]);
  r.u[3] = cvtpk(b[2], b[3]);
  return r.v;
}
// async global->LDS, 4 bytes per lane, LDS dest = ldsbase + lane*4 (wave-uniform base)
static __device__ __forceinline__ void gload_lds4(const float* g, float* lds) {
  __builtin_amdgcn_global_load_lds((const __attribute__((address_space(1))) void*)g,
                                   (__attribute__((address_space(3))) void*)lds, 4, 0, 0);
}

// ---------------- degree count ----------------
__global__ __launch_bounds__(256) void k_count(const int* __restrict__ dst, int* __restrict__ cnt) {
  int t = blockIdx.x * 256 + threadIdx.x;
  if (t < NE) atomicAdd(&cnt[dst[t]], 1);
}

// ---------------- scan: rowptr = exclusive prefix of cnt ----------------
__global__ __launch_bounds__(1024) void k_scan_local(const int* __restrict__ cnt, int* __restrict__ rowptr,
                                                     int* __restrict__ bsum) {
  __shared__ int sm[1024];
  int tid = threadIdx.x, t = blockIdx.x * 1024 + tid;
  int v = (t < NN) ? cnt[t] : 0;
  sm[tid] = v;
  __syncthreads();
  for (int off = 1; off < 1024; off <<= 1) {
    int y = (tid >= off) ? sm[tid - off] : 0;
    __syncthreads();
    sm[tid] += y;
    __syncthreads();
  }
  if (t < NN) rowptr[t] = sm[tid] - v;  // local exclusive
  if (tid == 1023) bsum[blockIdx.x] = sm[tid];
}
__global__ __launch_bounds__(128) void k_scan_bsum(int* __restrict__ bsum) {
  __shared__ int sm[128];
  int tid = threadIdx.x;
  int v = (tid < NB_SCAN) ? bsum[tid] : 0;
  sm[tid] = v;
  __syncthreads();
  for (int off = 1; off < 128; off <<= 1) {
    int y = (tid >= off) ? sm[tid - off] : 0;
    __syncthreads();
    sm[tid] += y;
    __syncthreads();
  }
  if (tid < NB_SCAN) bsum[tid] = sm[tid] - v;  // exclusive
}
__global__ __launch_bounds__(1024) void k_scan_add(int* __restrict__ rowptr, const int* __restrict__ bsum) {
  int t = blockIdx.x * 1024 + threadIdx.x;
  if (t < NN) rowptr[t] += bsum[t >> 10];
  if (t == 0) rowptr[NN] = NE;
}

// ---------------- bucket sort edges by dst: esorted[j] = src ----------------
__global__ __launch_bounds__(256) void k_sort(const int* __restrict__ src, const int* __restrict__ dst,
                                              const int* __restrict__ rowptr, int* __restrict__ epos,
                                              int* __restrict__ esorted) {
  int t = blockIdx.x * 256 + threadIdx.x;
  if (t >= NE) return;
  int d = dst[t];
  int p = atomicAdd(&epos[d], 1);
  esorted[rowptr[d] + p] = src[t];
}

// ------------- weight prep: fragment-ordered bf16, K padded to 640 -------------
// wf[(((ct*20)+ks)*64 + lane)*8 + i] = W[k = ks*32 + (lane>>4)*8 + i][c = ct*16 + (lane&15)]
// ct in [0,16): Wl (cols 0..255); ct in [16,32): Wr (cols 256..511). k>=602 -> 0.
__global__ __launch_bounds__(256) void k_prep_w1(const float* __restrict__ Wl, const float* __restrict__ Wr,
                                                 short* __restrict__ wf) {
  int idx = blockIdx.x * 256 + threadIdx.x;
  if (idx >= 32 * 20 * 512) return;
  int i = idx & 7, l = (idx >> 3) & 63, rest = idx >> 9;
  int ks = rest % 20, ct = rest / 20;
  int c = ct * 16 + (l & 15);
  int k = ks * 32 + ((l >> 4) << 3) + i;
  float v = 0.f;
  if (k < FIN) v = (c < HID) ? Wl[k * HID + c] : Wr[k * HID + (c - HID)];
  wf[idx] = f2bf(v);
}
__global__ __launch_bounds__(256) void k_prep_w2(const float* __restrict__ Wl, const float* __restrict__ Wr,
                                                 short* __restrict__ wf) {
  int idx = blockIdx.x * 256 + threadIdx.x;
  if (idx >= 6 * 8 * 512) return;
  int i = idx & 7, l = (idx >> 3) & 63, rest = idx >> 9;
  int ks = rest & 7, ct = rest >> 3;
  int c = ct * 16 + (l & 15);
  int k = ks * 32 + ((l >> 4) << 3) + i;
  float v = 0.f;
  if (c < NC) v = Wl[k * NC + c];
  else if (c < 2 * NC) v = Wr[k * NC + (c - NC)];
  wf[idx] = f2bf(v);
}

// -------- layer-1 GEMM: bn=0: t1 = bf16(x@Wl1); bn=1: t2 = bf16(x@Wr1) --------
// grid (782, 2). Block: 512 thr = 8 waves as 4 row-groups x 2 col-groups.
// Block tile 128 rows x 256 cols; wave tile 32x128; acc[2][8] = 64 AGPR -> 2 waves/SIMD.
// LDS 2x32KB double buffer -> 2 blocks/CU -> 16 waves/CU (~50% occ).
// Weight amortization: BM=128 halves per-output weight L2 traffic vs BM=64; the 4
// row-groups re-read identical fragments (L1 hits).
// VMEM issue order per iter (FIFO-critical): [16 weight b128] -> [16 stage gload_lds].
// LDS swizzle: 16B-quad pq = lq ^ (row&15) (involution; stage pre-swizzles global k).
__global__ __launch_bounds__(512, 2) void k_gemm_l1(const float* __restrict__ x, const short* __restrict__ wf,
                                                    short* __restrict__ t1, short* __restrict__ t2) {
  __shared__ float xs[2][128 * 64];  // 2 x 32KB
  const int lane = threadIdx.x & 63;
  const int w = threadIdx.x >> 6;
  const int lr = lane & 15, lg = lane >> 4;
  const int wc = w & 1, wr = w >> 1;
  const int row0 = blockIdx.x * 128;
  const int bn = blockIdx.y;  // 0 -> Wl/t1, 1 -> Wr/t2

  f32x4 acc[2][8];
#pragma unroll
  for (int a = 0; a < 2; ++a)
#pragma unroll
    for (int b = 0; b < 8; ++b)
      acc[a][b] = (f32x4){0.f, 0.f, 0.f, 0.f};

  const short* wb = wf + (size_t)(bn * 16 + wc * 8) * 20 * 512 + lane * 8;

  const int s_pq = lane >> 2, s_pe = lane & 3;

#define STAGE(KS, BUF)                                                             \
  {                                                                                \
    _Pragma("unroll")                                                              \
    for (int q = 0; q < 16; ++q) {                                                 \
      int r = w * 16 + q;                                                          \
      int rs = row0 + r; rs = rs < NN ? rs : NN - 1;                               \
      int ld = ((s_pq ^ (r & 15)) << 2) | s_pe;                                    \
      int k = (KS) * 64 + ld; k = k < FIN ? k : 0;                                 \
      gload_lds4(x + (size_t)rs * FIN + k, &xs[BUF][r * 64]);                      \
    }                                                                              \
  }

  STAGE(0, 0);
  __syncthreads();

  for (int ks = 0; ks < 10; ++ks) {
    const int cur = ks & 1;
    // (1) weight loads FIRST (both substeps) — FIFO keeps stage in flight
    bf16x8 bb0[8], bb1[8];
#pragma unroll
    for (int c = 0; c < 8; ++c) bb0[c] = *(const bf16x8*)(wb + (size_t)(c * 20 + ks * 2) * 512);
#pragma unroll
    for (int c = 0; c < 8; ++c) bb1[c] = *(const bf16x8*)(wb + (size_t)(c * 20 + ks * 2 + 1) * 512);
    // (2) stage next K-tile
    if (ks < 9) STAGE(ks + 1, cur ^ 1);
    // (3) two 32-wide substeps from LDS
#pragma unroll
    for (int s = 0; s < 2; ++s) {
      bf16x8 af[2];
#pragma unroll
      for (int t = 0; t < 2; ++t) {
        int row = wr * 32 + t * 16 + lr;
        const char* rowp = (const char*)&xs[cur][row * 64];
        int lq0 = s * 8 + lg * 2;
        f32x4 v0 = *(const f32x4*)(rowp + ((((lq0 + 0) ^ lr) & 15) << 4));
        f32x4 v1 = *(const f32x4*)(rowp + ((((lq0 + 1) ^ lr) & 15) << 4));
        af[t] = pack8q(v0, v1);
      }
#pragma unroll
      for (int c = 0; c < 8; ++c) {
        bf16x8 bbv = s ? bb1[c] : bb0[c];
#pragma unroll
        for (int t = 0; t < 2; ++t)
          acc[t][c] = __builtin_amdgcn_mfma_f32_16x16x32_bf16(af[t], bbv, acc[t][c], 0, 0, 0);
      }
    }
    __syncthreads();
  }
#undef STAGE

  short* dstb = (bn == 0) ? t1 : t2;
#pragma unroll
  for (int t = 0; t < 2; ++t)
#pragma unroll
    for (int c = 0; c < 8; ++c)
#pragma unroll
      for (int j = 0; j < 4; ++j) {
        int row = row0 + wr * 32 + t * 16 + lg * 4 + j;
        if (row < NN) {
          int col = wc * 128 + c * 16 + lr;
          dstb[(size_t)row * HID + col] = f2bf(acc[t][c][j]);
        }
      }
}

// ---- gather1 (fused combine): h = relu(mean(t1[nbrs]) + bl1 + t2[n]), IN-PLACE over t2 ----
// 4-deep manual load pipeline: 4 independent row loads in flight per step.
__global__ __launch_bounds__(256) void k_gather1(const short* __restrict__ t1, short* __restrict__ t2h,
                                                 const int* __restrict__ rowptr, const int* __restrict__ esorted,
                                                 const float* __restrict__ bl) {
  int t = blockIdx.x * 256 + threadIdx.x;
  int n = t >> 6, lane = t & 63;
  if (n >= NN) return;
  s16x4 tv = *(const s16x4*)(t2h + (size_t)n * HID + lane * 4);  // own row, read before write
  int beg = rowptr[n], end = rowptr[n + 1];
  float a0 = 0.f, a1 = 0.f, a2 = 0.f, a3 = 0.f;
  int j = beg;
  for (; j + 4 <= end; j += 4) {
    int s0 = esorted[j], s1 = esorted[j + 1], s2 = esorted[j + 2], s3 = esorted[j + 3];
    s16x4 v0 = *(const s16x4*)(t1 + (size_t)s0 * HID + lane * 4);
    s16x4 v1 = *(const s16x4*)(t1 + (size_t)s1 * HID + lane * 4);
    s16x4 v2 = *(const s16x4*)(t1 + (size_t)s2 * HID + lane * 4);
    s16x4 v3 = *(const s16x4*)(t1 + (size_t)s3 * HID + lane * 4);
    a0 += bf2f(v0[0]) + bf2f(v1[0]) + bf2f(v2[0]) + bf2f(v3[0]);
    a1 += bf2f(v0[1]) + bf2f(v1[1]) + bf2f(v2[1]) + bf2f(v3[1]);
    a2 += bf2f(v0[2]) + bf2f(v1[2]) + bf2f(v2[2]) + bf2f(v3[2]);
    a3 += bf2f(v0[3]) + bf2f(v1[3]) + bf2f(v2[3]) + bf2f(v3[3]);
  }
  for (; j < end; ++j) {
    int s = esorted[j];
    s16x4 v = *(const s16x4*)(t1 + (size_t)s * HID + lane * 4);
    a0 += bf2f(v[0]); a1 += bf2f(v[1]); a2 += bf2f(v[2]); a3 += bf2f(v[3]);
  }
  int deg = end - beg;
  float inv = 1.0f / (float)(deg > 1 ? deg : 1);
  f32x4 b = *(const f32x4*)(bl + lane * 4);
  s16x4 o;
  float v0 = a0 * inv + b[0] + bf2f(tv[0]);
  float v1 = a1 * inv + b[1] + bf2f(tv[1]);
  float v2 = a2 * inv + b[2] + bf2f(tv[2]);
  float v3 = a3 * inv + b[3] + bf2f(tv[3]);
  o[0] = f2bf(v0 > 0.f ? v0 : 0.f);
  o[1] = f2bf(v1 > 0.f ? v1 : 0.f);
  o[2] = f2bf(v2 > 0.f ? v2 : 0.f);
  o[3] = f2bf(v3 > 0.f ? v3 : 0.f);
  *(s16x4*)(t2h + (size_t)n * HID + lane * 4) = o;
}

// ---------------- GEMM2: u[N,96] = h[N,256] @ [Wl2|Wr2] (cols 84..95 pad) ----------------
__global__ __launch_bounds__(256) void k_gemm2(const short* __restrict__ h, const short* __restrict__ wf,
                                               float* __restrict__ u) {
  const int lane = threadIdx.x & 63;
  const int w = threadIdx.x >> 6;
  const int lr = lane & 15, lg = lane >> 4;
  const int row0 = blockIdx.x * 128 + w * 32;

  f32x4 acc[2][6];
#pragma unroll
  for (int a = 0; a < 2; ++a)
#pragma unroll
    for (int b = 0; b < 6; ++b)
      acc[a][b] = (f32x4){0.f, 0.f, 0.f, 0.f};

  const int r0 = row0 + lr, r1 = row0 + 16 + lr;
#pragma unroll
  for (int ks = 0; ks < 8; ++ks) {
    bf16x8 a0, a1;
#pragma unroll
    for (int i = 0; i < 8; ++i) { a0[i] = 0; a1[i] = 0; }
    if (r0 < NN) a0 = *(const bf16x8*)(h + (size_t)r0 * HID + ks * 32 + lg * 8);
    if (r1 < NN) a1 = *(const bf16x8*)(h + (size_t)r1 * HID + ks * 32 + lg * 8);
    bf16x8 bfrag[6];
#pragma unroll
    for (int ct = 0; ct < 6; ++ct)
      bfrag[ct] = *(const bf16x8*)(wf + (size_t)((ct * 8 + ks) * 64 + lane) * 8);
#pragma unroll
    for (int ct = 0; ct < 6; ++ct) {
      acc[0][ct] = __builtin_amdgcn_mfma_f32_16x16x32_bf16(a0, bfrag[ct], acc[0][ct], 0, 0, 0);
      acc[1][ct] = __builtin_amdgcn_mfma_f32_16x16x32_bf16(a1, bfrag[ct], acc[1][ct], 0, 0, 0);
    }
  }
#pragma unroll
  for (int rt = 0; rt < 2; ++rt)
#pragma unroll
    for (int ct = 0; ct < 6; ++ct)
#pragma unroll
      for (int j = 0; j < 4; ++j) {
        int row = row0 + rt * 16 + lg * 4 + j;
        int col = ct * 16 + lr;
        if (row < NN) u[(size_t)row * 96 + col] = acc[rt][ct][j];
      }
}

// ---------------- final: log_softmax(mean(u[nbrs,0:42]) + bl2 + u[:,42:84]) ----------------
__global__ __launch_bounds__(256) void k_final(const float* __restrict__ u, const int* __restrict__ rowptr,
                                               const int* __restrict__ esorted, const float* __restrict__ bl,
                                               float* __restrict__ out) {
  int t = blockIdx.x * 256 + threadIdx.x;
  int n = t >> 6, c = t & 63;
  if (n >= NN) return;
  int beg = rowptr[n], end = rowptr[n + 1];
  float a = 0.f;
  if (c < NC) {
    int j = beg;
    for (; j + 4 <= end; j += 4) {
      int s0 = esorted[j], s1 = esorted[j + 1], s2 = esorted[j + 2], s3 = esorted[j + 3];
      float u0 = u[(size_t)s0 * 96 + c];
      float u1 = u[(size_t)s1 * 96 + c];
      float u2 = u[(size_t)s2 * 96 + c];
      float u3 = u[(size_t)s3 * 96 + c];
      a += (u0 + u1) + (u2 + u3);
    }
    for (; j < end; ++j) a += u[(size_t)esorted[j] * 96 + c];
  }
  int deg = end - beg;
  float inv = 1.0f / (float)(deg > 1 ? deg : 1);
  float v = (c < NC) ? (a * inv + bl[c] + u[(size_t)n * 96 + NC + c]) : -1e30f;
  float m = v;
#pragma unroll
  for (int off = 32; off > 0; off >>= 1) m = fmaxf(m, __shfl_xor(m, off));
  float e = (c < NC) ? __expf(v - m) : 0.f;
#pragma unroll
  for (int off = 32; off > 0; off >>= 1) e += __shfl_xor(e, off);
  float lse = __logf(e);
  if (c < NC) out[(size_t)n * NC + c] = v - m - lse;
}

extern "C" void kernel_launch(void* const* d_in, const int* in_sizes, int n_in,
                              void* d_out, int out_size, void* d_ws, size_t ws_size,
                              hipStream_t stream) {
  const float* x   = (const float*)d_in[0];
  const int* eidx  = (const int*)d_in[1];
  const float* Wl1 = (const float*)d_in[2];
  const float* bl1 = (const float*)d_in[3];
  const float* Wr1 = (const float*)d_in[4];
  const float* Wl2 = (const float*)d_in[5];
  const float* bl2 = (const float*)d_in[6];
  const float* Wr2 = (const float*)d_in[7];
  float* out = (float*)d_out;
  const int* src = eidx;
  const int* dstp = eidx + NE;

  // workspace layout (bytes) — peak 106,700,800 B (validated footprint)
  char* ws = (char*)d_ws;
  int*   cnt     = (int*)(ws + 0);            //   400,000
  int*   rowptr  = (int*)(ws + 524288);       //   400,004
  int*   epos    = (int*)(ws + 1048576);      //   400,000
  int*   bsum    = (int*)(ws + 1462272);      //       392
  short* wf1     = (short*)(ws + 1572864);    //   655,360 (fits 786,432 slot)
  short* wf2     = (short*)(ws + 2359296);    //    49,152
  int*   esorted = (int*)(ws + 2621440);      // 1,600,000  (ends 4,221,440)
  short* t1      = (short*)(ws + 4300800);    // 51,200,000 (ends 55,500,800)
  short* t2h     = (short*)(ws + 55500800);   // 51,200,000 (ends 106,700,800); becomes h in-place
  float* u       = (float*)(ws + 4300800);    // 38,400,000 — t1 dead after gather1

  hipMemsetAsync(cnt, 0, (size_t)NN * sizeof(int), stream);
  hipMemsetAsync(epos, 0, (size_t)NN * sizeof(int), stream);
  k_prep_w1<<<(32 * 20 * 512 + 255) / 256, 256, 0, stream>>>(Wl1, Wr1, wf1);
  k_prep_w2<<<(6 * 8 * 512 + 255) / 256, 256, 0, stream>>>(Wl2, Wr2, wf2);
  k_count<<<(NE + 255) / 256, 256, 0, stream>>>(dstp, cnt);
  k_scan_local<<<NB_SCAN, 1024, 0, stream>>>(cnt, rowptr, bsum);
  k_scan_bsum<<<1, 128, 0, stream>>>(bsum);
  k_scan_add<<<NB_SCAN, 1024, 0, stream>>>(rowptr, bsum);
  k_sort<<<(NE + 255) / 256, 256, 0, stream>>>(src, dstp, rowptr, epos, esorted);
  dim3 g1((NN + 127) / 128, 2);
  k_gemm_l1<<<g1, 512, 0, stream>>>(x, wf1, t1, t2h);
  k_gather1<<<(NN * 64) / 256, 256, 0, stream>>>(t1, t2h, rowptr, esorted, bl1);
  k_gemm2<<<(NN + 127) / 128, 256, 0, stream>>>(t2h, wf2, u);
  k_final<<<(NN * 64) / 256, 256, 0, stream>>>(u, rowptr, esorted, bl2, out);
}